// Round 5
// baseline (151.054 us; speedup 1.0000x reference)
//
#include <hip/hip_runtime.h>

#define TS 64
#define NB 256
#define DI 32
#define NH 10
#define IND 42

// DPP quad_perm xor-exchange: 0xB1 = xor1, 0x4E = xor2 (VALU pipe)
template<int CTRL>
__device__ __forceinline__ float dppx(float v){
  return __int_as_float(__builtin_amdgcn_update_dpp(
      0, __float_as_int(v), CTRL, 0xF, 0xF, true));
}

// uniform broadcast from a fixed lane: VALU->SGPR, no LDS
__device__ __forceinline__ float rl(float v, int lane){
  return __int_as_float(__builtin_amdgcn_readlane(__float_as_int(v), lane));
}

// opaque single-value register pin: blocks rematerialization from LDS
__device__ __forceinline__ void pin(float& x){ asm volatile("" : "+v"(x)); }

__device__ __forceinline__ float sigm(float x){ return 1.f/(1.f + __expf(-x)); }
__device__ __forceinline__ float tanhr(float x){ float e = __expf(2.f*x); return 1.f - 2.f/(e + 1.f); }

// combined U = RY(t3)*RX(t2)*RZ(t1) -> 8 floats (row0 r/i pairs, row1 r/i pairs)
__device__ __forceinline__ void mkU(float t1, float t2, float t3, float* dst){
  float c1 = __cosf(0.5f*t1), s1 = __sinf(0.5f*t1);
  float c2 = __cosf(0.5f*t2), s2 = __sinf(0.5f*t2);
  float c3 = __cosf(0.5f*t3), s3 = __sinf(0.5f*t3);
  float A00r =  c2*c1, A00i = -c2*s1;
  float A01r =  s2*s1, A01i = -s2*c1;
  float A10r = -s2*s1, A10i = -s2*c1;
  float A11r =  c2*c1, A11i =  c2*s1;
  dst[0] = c3*A00r - s3*A10r; dst[1] = c3*A00i - s3*A10i;
  dst[2] = c3*A01r - s3*A11r; dst[3] = c3*A01i - s3*A11i;
  dst[4] = s3*A00r + c3*A10r; dst[5] = s3*A00i + c3*A10i;
  dst[6] = s3*A01r + c3*A11r; dst[7] = s3*A01i + c3*A11i;
}

// quadratic form q00*c^2 + q11*s^2 + q01*c*s  ->  (alpha, beta, gamma) s.t.
// value = alpha + beta*cos(th) + gamma*sin(th), with (c,s)=(cos(th/2),sin(th/2))
__device__ __forceinline__ float3 qf(float q00, float q11, float q01){
  return make_float3(0.5f*(q00+q11), 0.5f*(q00-q11), 0.5f*q01);
}
__device__ __forceinline__ float qeval(float3 q, float C, float S){
  return fmaf(q.y, C, fmaf(q.z, S, q.x));
}

// R17: 2 batch elements per block (512 thr, 8 waves, grid 128).
// R16 post-mortem: full register residency (VGPR 132) changed nothing ->
// the loop is ~50% stall (barrier + ds_read exchange + trans latency) and
// at 1 wave/SIMD every stall idles the SIMD. Folding 2 independent
// recurrences into one block gives each SIMD 2 waves whose stalls mutually
// hide (MLP on the exchange, issue interleave on the chains). Half the CUs
// idle -- irrelevant, wall time is latency-set. No math changes.
// waves_per_eu(2,2) -> 256-VGPR budget, our ~132 still spill-free.
__global__ __launch_bounds__(512) __attribute__((amdgpu_waves_per_eu(2, 2)))
void qlstm_kernel(const float* __restrict__ xin,
                  const float* __restrict__ qp,
                  const float* __restrict__ Wf, const float* __restrict__ bfp,
                  const float* __restrict__ Wi, const float* __restrict__ bip,
                  const float* __restrict__ Wg, const float* __restrict__ bgp,
                  const float* __restrict__ Wo, const float* __restrict__ bop,
                  float* __restrict__ out)
{
  __shared__ float lx[2][TS][DI + 1];                // staged x, +1 pad
  __shared__ float lwx[2][4][TS][NH];                // precomputed W.x + bias
  __shared__ __align__(16) float lBw[2][4][NH][4];   // B_w = U2^dag Z U2
  __shared__ __align__(16) float lq[2][2][NH][4];    // [sub][buf][h][gate]

  const int tid  = threadIdx.x;
  const int sub  = tid >> 8;                 // 0/1: which batch elem in block
  const int b    = blockIdx.x * 2 + sub;
  const int g    = (tid >> 6) & 3;
  const int lane = tid & 63;
  const int hq   = lane >> 2;        // mask index (valid < 10)
  const int sg   = lane & 3;         // 0:sigma0 1:H1 2:H2 3:sigma3
  const int hrow = (lane < NH) ? lane : 0;

  const float* Wsel = (g==0) ? Wf : (g==1) ? Wi : (g==2) ? Wg : Wo;
  const float* bsel = (g==0) ? bfp : (g==1) ? bip : (g==2) ? bgp : bop;

  // ---- stage x coalesced (both batch elems) ----
  for (int i = tid; i < 2*TS*DI; i += 512) {
    int ss = i >> 11, r = i & 2047, tt = r >> 5, d = r & 31;
    lx[ss][tt][d] = xin[(size_t)tt*(NB*DI) + (size_t)(blockIdx.x*2 + ss)*DI + d];
  }
  // ---- layer-2 B matrices (redundant across subs, harmless) ----
  if (lane < NH) {
    float u[8];
    mkU(qp[30 + lane*3 + 0], qp[30 + lane*3 + 1], qp[30 + lane*3 + 2], u);
    float B00 = u[0]*u[0]+u[1]*u[1] - (u[4]*u[4]+u[5]*u[5]);
    float B11 = u[2]*u[2]+u[3]*u[3] - (u[6]*u[6]+u[7]*u[7]);
    float B01r= u[0]*u[2]+u[1]*u[3] - (u[4]*u[6]+u[5]*u[7]);
    float B01i= u[1]*u[2]-u[0]*u[3] - (u[5]*u[6]-u[4]*u[7]);
    *reinterpret_cast<float4*>(&lBw[sub][g][lane][0]) = make_float4(B00,B11,B01r,B01i);
  }
  __syncthreads();

  // ---- precompute W.x + bias for all t (lane == t), wave-private ----
  {
    float acc[NH];
    #pragma unroll
    for (int h = 0; h < NH; h++) acc[h] = bsel[h];
    for (int k = 0; k < DI; k++) {
      float xk = lx[sub][lane][k];
      #pragma unroll
      for (int h = 0; h < NH; h++) acc[h] = fmaf(Wsel[h*IND + k], xk, acc[h]);
    }
    #pragma unroll
    for (int h = 0; h < NH; h++) lwx[sub][g][lane][h] = acc[h];
  }
  // (same-wave LDS visibility via lgkmcnt)

  // ---- register-resident recurrent weights + conv-data quadratic forms ----
  float wh[NH];
  #pragma unroll
  for (int j = 0; j < NH; j++) wh[j] = Wsel[hrow*IND + DI + j];

  // quadratic-form constants for (n0, n1, e1r, e1i) of wire hrow:
  //   v = U1.[c;s];  wire 0 uses (A0,A1)=(v0,v1); wires>=1 use ((v0+v1)/2,(v0-v1)/2)
  float3 Qn0, Qn1, Qer, Qei;
  {
    float U1[8];
    mkU(qp[hrow*3+0], qp[hrow*3+1], qp[hrow*3+2], U1);
    // rows of U1 as complex pairs
    float r00r=U1[0], r00i=U1[1], r01r=U1[2], r01i=U1[3];
    float r10r=U1[4], r10i=U1[5], r11r=U1[6], r11i=U1[7];
    float P0r,P0i,P1r,P1i, R0r,R0i,R1r,R1i;
    if (lane == 0) {
      P0r=r00r; P0i=r00i; P1r=r01r; P1i=r01i;
      R0r=r10r; R0i=r10i; R1r=r11r; R1i=r11i;
    } else {
      P0r=0.5f*(r00r+r10r); P0i=0.5f*(r00i+r10i);
      P1r=0.5f*(r01r+r11r); P1i=0.5f*(r01i+r11i);
      R0r=0.5f*(r00r-r10r); R0i=0.5f*(r00i-r10i);
      R1r=0.5f*(r01r-r11r); R1i=0.5f*(r01i-r11i);
    }
    Qn0 = qf(P0r*P0r+P0i*P0i, P1r*P1r+P1i*P1i, 2.f*(P0r*P1r+P0i*P1i));
    Qn1 = qf(R0r*R0r+R0i*R0i, R1r*R1r+R1i*R1i, 2.f*(R0r*R1r+R0i*R1i));
    Qer = qf(R0r*P0r+R0i*P0i, R1r*P1r+R1i*P1i,
             (R0r*P1r+R0i*P1i) + (R1r*P0r+R1i*P0i));
    Qei = qf(R0i*P0r-R0r*P0i, R1i*P1r-R1r*P1i,
             (R0i*P1r-R0r*P1i) + (R1i*P0r-R1r*P0i));
  }

  // ---- per-lane chain init constants (k's), pw folded in via linearity ----
  float4 b0 = *reinterpret_cast<const float4*>(&lBw[sub][g][0][0]);
  if (hq == 0) b0 = make_float4(1.f, 1.f, 0.f, 0.f);   // E0 mask excludes wire 0
  float k0, k3, ka, kb;
  if      (sg == 0) { k0 = b0.x;  k3 = b0.y;  ka = b0.z; kb = -b0.w; }
  else if (sg == 1) { k0 = b0.z;  k3 = b0.z;  ka = 0.5f*(b0.x + b0.y); kb = 0.f; }
  else if (sg == 2) { k0 = -b0.w; k3 = b0.w;  ka = 0.f;  kb = 0.5f*(b0.y - b0.x); }
  else              { k0 = b0.y;  k3 = b0.x;  ka = b0.z; kb = b0.w; }
  {
    const float pw = (sg == 1) ? 2.f : (sg == 2) ? -2.f : 1.f;
    k0 *= pw; k3 *= pw; ka *= pw; kb *= pw;
  }

  float C00[9], C11[9], Cr[9], Ci[9];
  #pragma unroll
  for (int w = 1; w <= 9; w++) {
    float4 bb = *reinterpret_cast<const float4*>(&lBw[sub][g][w][0]);
    bool inM = (hq == 0) || (w <= hq);        // M_0={1..9}, M_h={0..h}
    C00[w-1] = inM ? bb.x : 1.f;
    C11[w-1] = inM ? bb.y : 1.f;
    Cr[w-1]  = inM ? bb.z : 0.f;
    Ci[w-1]  = inM ? bb.w : 0.f;
  }

  // ---- pin chain constants into VGPRs (free at 2-wave/EU budget) ----
  #pragma unroll
  for (int w = 0; w < 9; w++) {
    pin(C00[w]); pin(C11[w]); pin(Cr[w]); pin(Ci[w]);
  }
  #pragma unroll
  for (int j = 0; j < NH; j++) pin(wh[j]);
  pin(Qn0.x); pin(Qn0.y); pin(Qn0.z);
  pin(Qn1.x); pin(Qn1.y); pin(Qn1.z);
  pin(Qer.x); pin(Qer.y); pin(Qer.z);
  pin(Qei.x); pin(Qei.y); pin(Qei.z);
  pin(k0); pin(k3); pin(ka); pin(kb);

  // wave-uniform activation constants: g==2 -> tanh(x) = 2*sigm(2x) - 1
  const float se = (g == 2) ? -2.f : -1.f;   // exp argument scale
  const float sa = (g == 2) ?  2.f :  1.f;
  const float sb = (g == 2) ? -1.f :  0.f;

  float cstate = 0.f, hval = 0.f;
  float wxcur = lwx[sub][g][0][hrow];      // prefetched W.x for t=0

  for (int t = 0; t < TS; t++) {
    const int tb = t & 1;

    // ---- (a) pre-activation: prefetched wx + tree-reduced recurrent dot ----
    float h0 = rl(hval,0), h1 = rl(hval,1), h2 = rl(hval,2), h3 = rl(hval,3), h4 = rl(hval,4);
    float h5 = rl(hval,5), h6 = rl(hval,6), h7 = rl(hval,7), h8 = rl(hval,8), h9 = rl(hval,9);
    float p0 = fmaf(wh[1], h1, wh[0]*h0);
    float p1 = fmaf(wh[3], h3, wh[2]*h2);
    float p2 = fmaf(wh[5], h5, wh[4]*h4);
    float p3 = fmaf(wh[7], h7, wh[6]*h6);
    float p4 = fmaf(wh[9], h9, wh[8]*h8);
    float pre = wxcur + ((p0 + p1) + (p2 + p3) + p4);

    // prefetch next step's W.x (latency hidden under the chain)
    wxcur = lwx[sub][g][(t+1) & (TS-1)][hrow];

    // full-angle sin/cos, no range reduction (|pre| small); 1/2pi inline const
    float th = pre * 0.15915494309189535f;
    float S = __builtin_amdgcn_sinf(th);
    float C = __builtin_amdgcn_cosf(th);
    float n0v  = qeval(Qn0, C, S);
    float n1v  = qeval(Qn1, C, S);
    float e1rv = qeval(Qer, C, S);
    float e1iv = qeval(Qei, C, S);

    // ---- (c) chain with broadcasts interleaved at point of use ----
    float vx0 = rl(n0v,0), vy0 = rl(n1v,0), vr0 = rl(e1rv,0), vi0 = rl(e1iv,0);
    float r0 = k0*vx0;
    float r3 = k3*vy0;
    float a  = ka*vr0 - kb*vi0;
    float bz = ka*vi0 + kb*vr0;
    #pragma unroll
    for (int w = 1; w <= 9; w++) {
      float vxw = rl(n0v, w), vyw = rl(n1v, w), vrw = rl(e1rv, w), viw = rl(e1iv, w);
      float q  = r0 + r3,  t2a = a + a;
      float u0 = q + t2a,  u3 = q - t2a;
      float s  = r0 - r3,  bb = bz + bz;          // u1 = (s, -bb)
      float m0 = u0 * vxw;
      float m3 = u3 * vyw;
      float am = s*vrw + bb*viw;                  // Re(u1*e1)
      float bm = s*viw - bb*vrw;                  // Im(u1*e1)
      float q2 = m0 + m3,  t2m = am + am;
      float y0 = q2 + t2m, y3 = q2 - t2m;
      float s2 = m0 - m3,  b2 = bm + bm;          // y1 = (s2, -b2)
      r0 = y0 * C00[w-1];
      r3 = y3 * C11[w-1];
      a  = s2*Cr[w-1] - b2*Ci[w-1];               // Re(y1*conj(C01))
      bz = -(s2*Ci[w-1] + b2*Cr[w-1]);            // Im(y1*conj(C01))
    }

    // ---- (d) weighted pick (pw pre-folded) + quad-sum; activation PRE-barrier ----
    float t0 = (sg & 1) ? a  : r0;
    float t1 = (sg & 1) ? r3 : bz;
    float Ee = (sg & 2) ? t1 : t0;
    Ee += dppx<0xB1>(Ee);
    Ee += dppx<0x4E>(Ee);
    if ((lane & 3) == 0 && hq < NH) {
      // single transcendental path: sigm for g!=2, 2*sigm(2x)-1 == tanh for g==2
      lq[sub][tb][hq][g] = fmaf(sa, 1.f/(1.f + __expf(se*Ee)), sb);
    }
    __syncthreads();   // the one barrier: activated-gate exchange (both subs)

    // ---- (f) LSTM cell: single b128 broadcast read of (f,i,g,o) ----
    float4 gates = *reinterpret_cast<const float4*>(&lq[sub][tb][hrow][0]);
    cstate = gates.x*cstate + gates.y*gates.z;
    hval = gates.w*tanhr(cstate);
    if (g == 0 && lane < NH) out[(size_t)t*(NB*NH) + b*NH + lane] = hval;
  }

  if (g == 0 && lane < NH) {
    out[(size_t)TS*NB*NH + b*NH + lane]          = hval;
    out[(size_t)TS*NB*NH + NB*NH + b*NH + lane]  = cstate;
  }
}

extern "C" void kernel_launch(void* const* d_in, const int* in_sizes, int n_in,
                              void* d_out, int out_size, void* d_ws, size_t ws_size,
                              hipStream_t stream) {
  (void)in_sizes; (void)n_in; (void)d_ws; (void)ws_size; (void)out_size;
  qlstm_kernel<<<dim3(NB/2), dim3(512), 0, stream>>>(
      (const float*)d_in[0], (const float*)d_in[1],
      (const float*)d_in[2], (const float*)d_in[3],
      (const float*)d_in[4], (const float*)d_in[5],
      (const float*)d_in[6], (const float*)d_in[7],
      (const float*)d_in[8], (const float*)d_in[9],
      (float*)d_out);
}

// Round 7
// 121.962 us; speedup vs baseline: 1.2385x; 1.2385x over previous
//
#include <hip/hip_runtime.h>

#define TS 64
#define NB 256
#define DI 32
#define NH 10
#define IND 42

// DPP quad_perm xor-exchange: 0xB1 = xor1, 0x4E = xor2 (VALU pipe)
template<int CTRL>
__device__ __forceinline__ float dppx(float v){
  return __int_as_float(__builtin_amdgcn_update_dpp(
      0, __float_as_int(v), CTRL, 0xF, 0xF, true));
}

// uniform broadcast from a fixed lane: VALU->SGPR, no LDS
__device__ __forceinline__ float rl(float v, int lane){
  return __int_as_float(__builtin_amdgcn_readlane(__float_as_int(v), lane));
}

// opaque single-value register pin: blocks rematerialization from LDS
__device__ __forceinline__ void pin(float& x){ asm volatile("" : "+v"(x)); }

__device__ __forceinline__ float tanhr(float x){ float e = __expf(2.f*x); return 1.f - 2.f/(e + 1.f); }

// combined U = RY(t3)*RX(t2)*RZ(t1) -> 8 floats (row0 r/i pairs, row1 r/i pairs)
__device__ __forceinline__ void mkU(float t1, float t2, float t3, float* dst){
  float c1 = __cosf(0.5f*t1), s1 = __sinf(0.5f*t1);
  float c2 = __cosf(0.5f*t2), s2 = __sinf(0.5f*t2);
  float c3 = __cosf(0.5f*t3), s3 = __sinf(0.5f*t3);
  float A00r =  c2*c1, A00i = -c2*s1;
  float A01r =  s2*s1, A01i = -s2*c1;
  float A10r = -s2*s1, A10i = -s2*c1;
  float A11r =  c2*c1, A11i =  c2*s1;
  dst[0] = c3*A00r - s3*A10r; dst[1] = c3*A00i - s3*A10i;
  dst[2] = c3*A01r - s3*A11r; dst[3] = c3*A01i - s3*A11i;
  dst[4] = s3*A00r + c3*A10r; dst[5] = s3*A00i + c3*A10i;
  dst[6] = s3*A01r + c3*A11r; dst[7] = s3*A01i + c3*A11i;
}

// quadratic form q00*c^2 + q11*s^2 + q01*c*s  ->  (alpha, beta, gamma) s.t.
// value = alpha + beta*cos(th) + gamma*sin(th), with (c,s)=(cos(th/2),sin(th/2))
__device__ __forceinline__ float3 qf(float q00, float q11, float q01){
  return make_float3(0.5f*(q00+q11), 0.5f*(q00-q11), 0.5f*q01);
}
__device__ __forceinline__ float qeval(float3 q, float C, float S){
  return fmaf(q.y, C, fmaf(q.z, S, q.x));
}

// One block per batch element. Wave g (0..3) = circuit g.
// R18 (resubmit after infra failure): revert to R16 structure (1 elem/block,
// best 56.7us) + transformed-basis chain. R17 subtraction model: Issue~1080,
// Stall~1050 cyc/step -> shrink issue. State (Q,S,A,Bn) =
// (r0+r3, r0-r3, 2a, -2bz): per-wire body drops 24 -> 19 VALU and ~1 dep
// level; C folded into 6 pre-scaled constants (Cp, Cm, 2Cr, 4Ci, 2Ci, 4Cr);
// masked wire = (2,0,0,0,0,0); pick/pw factors folded into init k by
// linearity (algebra re-verified vs R16 component-by-component).
__global__ __launch_bounds__(256) __attribute__((amdgpu_waves_per_eu(1, 1)))
void qlstm_kernel(const float* __restrict__ xin,
                  const float* __restrict__ qp,
                  const float* __restrict__ Wf, const float* __restrict__ bfp,
                  const float* __restrict__ Wi, const float* __restrict__ bip,
                  const float* __restrict__ Wg, const float* __restrict__ bgp,
                  const float* __restrict__ Wo, const float* __restrict__ bop,
                  float* __restrict__ out)
{
  __shared__ float lx[TS][DI + 1];                // staged x, +1 pad
  __shared__ float lwx[4][TS][NH];                // precomputed W.x + bias
  __shared__ __align__(16) float lBw[4][NH][4];   // B_w = U2^dag Z U2
  __shared__ __align__(16) float lq[2][NH][4];    // [buf][h][gate] -> b128 read

  const int tid  = threadIdx.x;
  const int b    = blockIdx.x;
  const int g    = tid >> 6;
  const int lane = tid & 63;
  const int hq   = lane >> 2;        // mask index (valid < 10)
  const int sg   = lane & 3;         // 0:sigma0 1:H1 2:H2 3:sigma3
  const int hrow = (lane < NH) ? lane : 0;

  const float* Wsel = (g==0) ? Wf : (g==1) ? Wi : (g==2) ? Wg : Wo;
  const float* bsel = (g==0) ? bfp : (g==1) ? bip : (g==2) ? bgp : bop;

  // ---- stage x coalesced ----
  for (int i = tid; i < TS*DI; i += 256) {
    int tt = i >> 5, d = i & 31;
    lx[tt][d] = xin[(size_t)tt*(NB*DI) + b*DI + d];
  }
  // ---- layer-2 B matrices ----
  if (lane < NH) {
    float u[8];
    mkU(qp[30 + lane*3 + 0], qp[30 + lane*3 + 1], qp[30 + lane*3 + 2], u);
    float B00 = u[0]*u[0]+u[1]*u[1] - (u[4]*u[4]+u[5]*u[5]);
    float B11 = u[2]*u[2]+u[3]*u[3] - (u[6]*u[6]+u[7]*u[7]);
    float B01r= u[0]*u[2]+u[1]*u[3] - (u[4]*u[6]+u[5]*u[7]);
    float B01i= u[1]*u[2]-u[0]*u[3] - (u[5]*u[6]-u[4]*u[7]);
    *reinterpret_cast<float4*>(&lBw[g][lane][0]) = make_float4(B00,B11,B01r,B01i);
  }
  __syncthreads();

  // ---- precompute W.x + bias for all t (lane == t), wave-private lwx[g] ----
  {
    float acc[NH];
    #pragma unroll
    for (int h = 0; h < NH; h++) acc[h] = bsel[h];
    #pragma unroll
    for (int k = 0; k < DI; k++) {
      float xk = lx[lane][k];
      #pragma unroll
      for (int h = 0; h < NH; h++) acc[h] = fmaf(Wsel[h*IND + k], xk, acc[h]);
    }
    #pragma unroll
    for (int h = 0; h < NH; h++) lwx[g][lane][h] = acc[h];
  }
  // (same-wave LDS visibility via lgkmcnt)

  // ---- register-resident recurrent weights + conv-data quadratic forms ----
  float wh[NH];
  #pragma unroll
  for (int j = 0; j < NH; j++) wh[j] = Wsel[hrow*IND + DI + j];

  // quadratic-form constants for (n0, n1, e1r, e1i) of wire hrow:
  //   v = U1.[c;s];  wire 0 uses (A0,A1)=(v0,v1); wires>=1 use ((v0+v1)/2,(v0-v1)/2)
  float3 Qn0, Qn1, Qer, Qei;
  {
    float U1[8];
    mkU(qp[hrow*3+0], qp[hrow*3+1], qp[hrow*3+2], U1);
    // rows of U1 as complex pairs
    float r00r=U1[0], r00i=U1[1], r01r=U1[2], r01i=U1[3];
    float r10r=U1[4], r10i=U1[5], r11r=U1[6], r11i=U1[7];
    float P0r,P0i,P1r,P1i, R0r,R0i,R1r,R1i;
    if (lane == 0) {
      P0r=r00r; P0i=r00i; P1r=r01r; P1i=r01i;
      R0r=r10r; R0i=r10i; R1r=r11r; R1i=r11i;
    } else {
      P0r=0.5f*(r00r+r10r); P0i=0.5f*(r00i+r10i);
      P1r=0.5f*(r01r+r11r); P1i=0.5f*(r01i+r11i);
      R0r=0.5f*(r00r-r10r); R0i=0.5f*(r00i-r10i);
      R1r=0.5f*(r01r-r11r); R1i=0.5f*(r01i-r11i);
    }
    Qn0 = qf(P0r*P0r+P0i*P0i, P1r*P1r+P1i*P1i, 2.f*(P0r*P1r+P0i*P1i));
    Qn1 = qf(R0r*R0r+R0i*R0i, R1r*R1r+R1i*R1i, 2.f*(R0r*R1r+R0i*R1i));
    Qer = qf(R0r*P0r+R0i*P0i, R1r*P1r+R1i*P1i,
             (R0r*P1r+R0i*P1i) + (R1r*P0r+R1i*P0i));
    Qei = qf(R0i*P0r-R0r*P0i, R1i*P1r-R1r*P1i,
             (R0i*P1r-R0r*P1i) + (R1i*P0r-R1r*P0i));
  }

  // ---- per-lane chain init constants; pick scale folded in via linearity ----
  float4 b0 = *reinterpret_cast<const float4*>(&lBw[g][0][0]);
  if (hq == 0) b0 = make_float4(1.f, 1.f, 0.f, 0.f);   // E0 mask excludes wire 0
  float k0, k3, ka, kb;
  if      (sg == 0) { k0 = b0.x;  k3 = b0.y;  ka = b0.z; kb = -b0.w; }
  else if (sg == 1) { k0 = b0.z;  k3 = b0.z;  ka = 0.5f*(b0.x + b0.y); kb = 0.f; }
  else if (sg == 2) { k0 = -b0.w; k3 = b0.w;  ka = 0.f;  kb = 0.5f*(b0.y - b0.x); }
  else              { k0 = b0.y;  k3 = b0.x;  ka = b0.z; kb = b0.w; }
  // new-basis pick returns (Q+S, A, Bn, Q-S) = (2r0, 2a, -2bz, 2r3) unscaled;
  // old weights pw = (1,2,-2,1) => fold gsc = (0.5, 1, 1, 0.5) into inits.
  {
    const float gsc = (sg == 0 || sg == 3) ? 0.5f : 1.0f;
    k0 *= gsc; k3 *= gsc; ka *= gsc; kb *= gsc;
  }
  float ka2 = ka + ka, kb2 = kb + kb;

  // ---- per-wire constants in the transformed basis ----
  float Cp[9], Cm[9], Cr2[9], Ci4[9], Ci2[9], Cr4[9];
  #pragma unroll
  for (int w = 1; w <= 9; w++) {
    float4 bb = *reinterpret_cast<const float4*>(&lBw[g][w][0]);
    bool inM = (hq == 0) || (w <= hq);        // M_0={1..9}, M_h={0..h}
    Cp[w-1]  = inM ? (bb.x + bb.y) : 2.f;
    Cm[w-1]  = inM ? (bb.x - bb.y) : 0.f;
    Cr2[w-1] = inM ? (bb.z + bb.z) : 0.f;
    Ci4[w-1] = inM ? (4.f * bb.w)  : 0.f;
    Ci2[w-1] = inM ? (bb.w + bb.w) : 0.f;
    Cr4[w-1] = inM ? (4.f * bb.z)  : 0.f;
  }

  // ---- pin chain constants into VGPRs (free at 1 wave/EU budget) ----
  #pragma unroll
  for (int w = 0; w < 9; w++) {
    pin(Cp[w]); pin(Cm[w]); pin(Cr2[w]); pin(Ci4[w]); pin(Ci2[w]); pin(Cr4[w]);
  }
  #pragma unroll
  for (int j = 0; j < NH; j++) pin(wh[j]);
  pin(Qn0.x); pin(Qn0.y); pin(Qn0.z);
  pin(Qn1.x); pin(Qn1.y); pin(Qn1.z);
  pin(Qer.x); pin(Qer.y); pin(Qer.z);
  pin(Qei.x); pin(Qei.y); pin(Qei.z);
  pin(k0); pin(k3); pin(ka2); pin(kb2);

  // wave-uniform activation constants: g==2 -> tanh(x) = 2*sigm(2x) - 1
  const float se = (g == 2) ? -2.f : -1.f;   // exp argument scale
  const float sa = (g == 2) ?  2.f :  1.f;
  const float sb = (g == 2) ? -1.f :  0.f;

  float cstate = 0.f, hval = 0.f;
  float wxcur = lwx[g][0][hrow];      // prefetched W.x for t=0

  for (int t = 0; t < TS; t++) {
    const int tb = t & 1;

    // ---- (a) pre-activation: prefetched wx + tree-reduced recurrent dot ----
    float h0 = rl(hval,0), h1 = rl(hval,1), h2 = rl(hval,2), h3 = rl(hval,3), h4 = rl(hval,4);
    float h5 = rl(hval,5), h6 = rl(hval,6), h7 = rl(hval,7), h8 = rl(hval,8), h9 = rl(hval,9);
    float p0 = fmaf(wh[1], h1, wh[0]*h0);
    float p1 = fmaf(wh[3], h3, wh[2]*h2);
    float p2 = fmaf(wh[5], h5, wh[4]*h4);
    float p3 = fmaf(wh[7], h7, wh[6]*h6);
    float p4 = fmaf(wh[9], h9, wh[8]*h8);
    float pre = wxcur + ((p0 + p1) + (p2 + p3) + p4);

    // prefetch next step's W.x (latency hidden under the chain)
    wxcur = lwx[g][(t+1) & (TS-1)][hrow];

    // full-angle sin/cos, no range reduction (|pre| small); 1/2pi inline const
    float th = pre * 0.15915494309189535f;
    float Sn_ = __builtin_amdgcn_sinf(th);
    float Cs_ = __builtin_amdgcn_cosf(th);
    float n0v  = qeval(Qn0, Cs_, Sn_);
    float n1v  = qeval(Qn1, Cs_, Sn_);
    float e1rv = qeval(Qer, Cs_, Sn_);
    float e1iv = qeval(Qei, Cs_, Sn_);

    // ---- (c) chain in transformed basis (Q,S,A,Bn) ----
    float vx0 = rl(n0v,0), vy0 = rl(n1v,0), vr0 = rl(e1rv,0), vi0 = rl(e1iv,0);
    float k0vx = k0 * vx0;
    float Q = fmaf(k3, vy0, k0vx);           // r0+r3 (scaled)
    float S = fmaf(-k3, vy0, k0vx);          // r0-r3
    float A = fmaf(-kb2, vi0, ka2*vr0);      // 2a
    float Bn = fmaf(-kb2, vr0, -(ka2*vi0)); // -2bz
    #pragma unroll
    for (int w = 1; w <= 9; w++) {
      float vxw = rl(n0v, w), vyw = rl(n1v, w), vrw = rl(e1rv, w), viw = rl(e1iv, w);
      float u0 = Q + A;
      float u3 = Q - A;
      float m0 = u0 * vxw;
      float m3 = u3 * vyw;
      float am = fmaf(-Bn, viw, S*vrw);       // S*vr + B*vi  (B = -Bn)
      float bm = fmaf( Bn, vrw, S*viw);       // S*vi - B*vr
      float q2  = m0 + m3;
      float s2  = m0 - m3;
      float am2 = am + am;
      float Qn2 = fmaf(am2, Cm[w-1], q2*Cp[w-1]);
      float Sn2 = fmaf(am2, Cp[w-1], q2*Cm[w-1]);
      float An2 = fmaf(s2, Cr2[w-1], -(bm*Ci4[w-1]));
      float Bn2 = fmaf(s2, Ci2[w-1],   bm*Cr4[w-1]);
      Q = Qn2; S = Sn2; A = An2; Bn = Bn2;
    }

    // ---- (d) pick (scales pre-folded) + quad-sum; activation PRE-barrier ----
    float QpS = Q + S;
    float QmS = Q - S;
    float t0 = (sg & 1) ? A   : QpS;
    float t1 = (sg & 1) ? QmS : Bn;
    float Ee = (sg & 2) ? t1 : t0;
    Ee += dppx<0xB1>(Ee);
    Ee += dppx<0x4E>(Ee);
    if ((lane & 3) == 0 && hq < NH) {
      // single transcendental path: sigm for g!=2, 2*sigm(2x)-1 == tanh for g==2
      lq[tb][hq][g] = fmaf(sa, 1.f/(1.f + __expf(se*Ee)), sb);
    }
    __syncthreads();   // the one barrier: activated-gate exchange

    // ---- (f) LSTM cell: single b128 broadcast read of (f,i,g,o) ----
    float4 gates = *reinterpret_cast<const float4*>(&lq[tb][hrow][0]);
    cstate = gates.x*cstate + gates.y*gates.z;
    hval = gates.w*tanhr(cstate);
    if (g == 0 && lane < NH) out[(size_t)t*(NB*NH) + b*NH + lane] = hval;
  }

  if (g == 0 && lane < NH) {
    out[(size_t)TS*NB*NH + b*NH + lane]          = hval;
    out[(size_t)TS*NB*NH + NB*NH + b*NH + lane]  = cstate;
  }
}

extern "C" void kernel_launch(void* const* d_in, const int* in_sizes, int n_in,
                              void* d_out, int out_size, void* d_ws, size_t ws_size,
                              hipStream_t stream) {
  (void)in_sizes; (void)n_in; (void)d_ws; (void)ws_size; (void)out_size;
  qlstm_kernel<<<dim3(NB), dim3(256), 0, stream>>>(
      (const float*)d_in[0], (const float*)d_in[1],
      (const float*)d_in[2], (const float*)d_in[3],
      (const float*)d_in[4], (const float*)d_in[5],
      (const float*)d_in[6], (const float*)d_in[7],
      (const float*)d_in[8], (const float*)d_in[9],
      (float*)d_out);
}